// Round 3
// baseline (3869.082 us; speedup 1.0000x reference)
//
#include <hip/hip_runtime.h>
#include <hip/hip_bf16.h>
#include <math.h>

// Problem constants
#define VV   32000
#define DD   300
#define HU   300
#define NC   3
#define BB   128
#define TT   512
#define N4H  1200
#define CHUNK 64
#define NCHUNK (TT / CHUNK)

// Recurrent kernel partition
#define GC   15   // col groups (units)
#define GR   16   // row groups
#define RPW  8    // rows per WG (BB/GR)
#define UPW  20   // units per WG (HU/GC)
#define KCH  12   // k-chunks (threads 0..239 active in GEMM)
#define KLEN 25   // k per chunk (KCH*KLEN = 300)

// Workspace layout: [zx (float)][ex (ulong, tagged h exchange)][cst][hfin]
static constexpr size_t ZX_F   = (size_t)BB * CHUNK * N4H;   // 9,830,400 floats
static constexpr size_t EX_W   = (size_t)2 * GR * RPW * HU;  // 76,800 ulongs
static constexpr size_t CST_F  = (size_t)BB * HU;            // 38,400 floats
static constexpr size_t HFIN_F = (size_t)BB * HU;            // 38,400 floats

typedef __attribute__((ext_vector_type(8))) short bf16x8;
typedef __attribute__((ext_vector_type(4))) float f32x4;
typedef unsigned long long ull;

__device__ __forceinline__ short f2bf(float f) {
    unsigned u = __float_as_uint(f);
    u += 0x7fff + ((u >> 16) & 1);   // round-to-nearest-even
    return (short)(u >> 16);
}
__device__ __forceinline__ float sigm(float x) { return 1.f / (1.f + __expf(-x)); }
__device__ __forceinline__ float tanh_(float x) { return 1.f - 2.f / (__expf(2.f * x) + 1.f); }

// ---------------------------------------------------------------------------
// init: zero exchange tags, c state, out[0]  (ws is poisoned 0xAA every launch)
// grid = 300 x 256 covers EX_W (76,800) and CST_F (38,400)
// ---------------------------------------------------------------------------
__global__ void init_kernel(ull* __restrict__ ex, float* __restrict__ cst,
                            float* __restrict__ out) {
    size_t i = (size_t)blockIdx.x * 256 + threadIdx.x;
    if (i < EX_W) ex[i] = 0ull;
    if (i < CST_F) cst[i] = 0.f;
    if (i == 0) out[0] = 0.f;
}

// ---------------------------------------------------------------------------
// Phase 1: zx[b][tc][n] = emb[ids[b][t0+tc]] @ W_lstm[0:300] + b_lstm   (bf16 MFMA)
// WG tile: M=256 rows, N=80 cols, K=320 (300 zero-padded). 4 waves, wave = 64x80.
// grid = (8192/256, 1200/80) = (32, 15)
// ---------------------------------------------------------------------------
__global__ __launch_bounds__(256) void zx_gemm(
    const float* __restrict__ emb, const int* __restrict__ ids,
    const float* __restrict__ Wl, const float* __restrict__ bl,
    float* __restrict__ zx, int t0)
{
    __shared__ short A_l[256 * 40];   // [row][k] pad 32->40 shorts
    __shared__ short B_l[80 * 40];    // [col][k] (transposed)
    __shared__ int   ids_l[256];

    const int tid = threadIdx.x;
    const int m0  = blockIdx.x * 256;
    const int n0  = blockIdx.y * 80;
    const int wv  = tid >> 6, ln = tid & 63;

    {   // per-row embedding id
        int m = m0 + tid;
        int b = m >> 6, tc = m & (CHUNK - 1);
        ids_l[tid] = ids[b * TT + t0 + tc];
    }

    f32x4 acc[4][5];
    for (int i = 0; i < 4; ++i)
        for (int j = 0; j < 5; ++j)
            acc[i][j] = (f32x4){0.f, 0.f, 0.f, 0.f};

    for (int k0 = 0; k0 < 320; k0 += 32) {
        __syncthreads();
        // stage A: 256 rows x 32 k, one row per thread (float4 x8, guard k<300)
        {
            const float* src = emb + (size_t)ids_l[tid] * DD;
            #pragma unroll
            for (int q = 0; q < 8; ++q) {
                int kg = k0 + q * 4;
                float4 v;
                if (kg < DD) v = *(const float4*)(src + kg);
                else         v = make_float4(0.f, 0.f, 0.f, 0.f);
                short4 s; s.x = f2bf(v.x); s.y = f2bf(v.y); s.z = f2bf(v.z); s.w = f2bf(v.w);
                *(short4*)&A_l[tid * 40 + q * 4] = s;
            }
        }
        // stage B (transposed): 80 cols x 32 k. thread: kk=tid>>3, 10 cols each
        {
            int kk = tid >> 3;
            int c0 = (tid & 7) * 10;
            int kg = k0 + kk;
            #pragma unroll
            for (int c = 0; c < 10; ++c) {
                float v = (kg < DD) ? Wl[(size_t)kg * N4H + n0 + c0 + c] : 0.f;
                B_l[(c0 + c) * 40 + kk] = f2bf(v);
            }
        }
        __syncthreads();
        // fragments + MFMA. A[m=lane&15][k=quad*8+j], B[k=quad*8+j][n=lane&15]
        const int koff = (ln >> 4) * 8;
        bf16x8 afr[4], bfr[5];
        #pragma unroll
        for (int mt = 0; mt < 4; ++mt) {
            int row = wv * 64 + mt * 16 + (ln & 15);
            afr[mt] = *(const bf16x8*)&A_l[row * 40 + koff];
        }
        #pragma unroll
        for (int nt = 0; nt < 5; ++nt) {
            int col = nt * 16 + (ln & 15);
            bfr[nt] = *(const bf16x8*)&B_l[col * 40 + koff];
        }
        #pragma unroll
        for (int mt = 0; mt < 4; ++mt)
            #pragma unroll
            for (int nt = 0; nt < 5; ++nt)
                acc[mt][nt] = __builtin_amdgcn_mfma_f32_16x16x32_bf16(
                    afr[mt], bfr[nt], acc[mt][nt], 0, 0, 0);
    }
    // epilogue: C row=(lane>>4)*4+reg, col=lane&15; add bias
    #pragma unroll
    for (int mt = 0; mt < 4; ++mt) {
        #pragma unroll
        for (int nt = 0; nt < 5; ++nt) {
            #pragma unroll
            for (int rg = 0; rg < 4; ++rg) {
                int row = m0 + wv * 64 + mt * 16 + (ln >> 4) * 4 + rg;
                int col = n0 + nt * 16 + (ln & 15);
                zx[(size_t)row * N4H + col] = acc[mt][nt][rg] + bl[col];
            }
        }
    }
}

// ---------------------------------------------------------------------------
// Phase 2: persistent recurrent kernel. 240 WGs = 16 row-groups x 15 col-groups.
// W_h slice in registers (thread owns 4 cols x 25 k = 100 VGPRs).
//
// Sync: SINGLE one-way trip. Each h value is an 8-B word (tag<<32 | f32 bits)
// stored with one relaxed agent-scope atomic store (atomic per word -> no
// drain, no separate flag). Consumers poll the data words directly (10 words
// per thread, all in flight) and drop accepted values straight into LDS.
// Tag for h_t is t+1; consumer at step t polls for tag >= t (h_{t-1}).
// Monotone tags + "producer reaches step t+1 only after consuming step t"
// make slot overwrite (t -> t+2, same parity) race-free without fences.
// ---------------------------------------------------------------------------
__global__ __launch_bounds__(256, 1) void lstm_rec(
    const float* __restrict__ zx, const float* __restrict__ Wl,
    const int* __restrict__ lens, ull* __restrict__ ex,
    float* __restrict__ cst, float* __restrict__ hfin, int t0)
{
    const int tid = threadIdx.x;
    const int rg  = blockIdx.x % GR;
    const int cgi = blockIdx.x / GR;
    const int r0  = rg * RPW;
    const int u0  = cgi * UPW;

    // GEMM role: cc in 0..19 (4 cols), kc in 0..11 (25 k); tid>=240 idle in GEMM
    const int cc = tid % 20;
    int kc = tid / 20;
    const bool gemm_act = (kc < KCH);
    if (!gemm_act) kc = KCH - 1;      // clamp so weight loads stay in-bounds

    // local col -> global gate col (4 consecutive cols never span a gate: 20%4==0)
    const int lc0  = cc * 4;
    const int gate = lc0 / UPW;
    const int ncol = 300 * gate + u0 + (lc0 % UPW);

    // W_h slice: unconditional load -> full register residency
    float4 w[KLEN];
    #pragma unroll
    for (int j = 0; j < KLEN; ++j) {
        int kh = kc * KLEN + j;  // h index
        w[j] = *(const float4*)(Wl + (size_t)(DD + kh) * N4H + ncol);
    }

    // poll role: threads 0..239 each own 10 consecutive words of one row
    const bool poller = (tid < 240);
    const int  pr = tid / 30;             // row 0..7
    const int  pu = (tid % 30) * 10;      // first unit of my 10

    __shared__ float h_l[RPW][304];          // staged h_{t-1}
    __shared__ float zp[KCH][RPW][84];       // k-chunk partials (pad 80->84)
    __shared__ float c_l[RPW][UPW];          // private cell state slice

    // gate role (tid < 160): u = tid%20, r = tid/20
    const int g_u = tid % UPW, g_r = tid / UPW;
    int mylen = 0;
    if (tid < RPW * UPW) {
        c_l[g_r][g_u] = cst[(size_t)(r0 + g_r) * HU + u0 + g_u];
        mylen = lens[r0 + g_r];
    }
    __syncthreads();

    for (int tc = 0; tc < CHUNK; ++tc) {
        const int t = t0 + tc;

        // prefetch zx for this step (independent of h; normal cached loads)
        float z_pre[4];
        if (tid < RPW * UPW) {
            const float* zrow = zx + ((size_t)(r0 + g_r) * CHUNK + tc) * N4H;
            #pragma unroll
            for (int gg = 0; gg < 4; ++gg)
                z_pre[gg] = zrow[300 * gg + u0 + g_u];
        }

        // ---- stage h_{t-1}: poll tagged words directly into LDS ----
        if (t == 0) {
            for (int i = tid; i < RPW * HU; i += 256)
                h_l[i / HU][i % HU] = 0.f;
        } else if (poller) {
            const ull* base = ex + (((size_t)(t & 1) * GR + rg) * RPW + pr) * HU + pu;
            ull v[10];
            unsigned pend = 0x3FFu;
            for (;;) {
                #pragma unroll
                for (int i = 0; i < 10; ++i)
                    if (pend & (1u << i))
                        v[i] = __hip_atomic_load(base + i, __ATOMIC_RELAXED,
                                                 __HIP_MEMORY_SCOPE_AGENT);
                unsigned np = 0;
                #pragma unroll
                for (int i = 0; i < 10; ++i)
                    if ((pend & (1u << i)) && ((int)(v[i] >> 32) < t))
                        np |= 1u << i;
                pend = np;
                if (!pend) break;
                __builtin_amdgcn_s_sleep(1);
            }
            #pragma unroll
            for (int i = 0; i < 10; ++i)
                h_l[pr][pu + i] = __uint_as_float((unsigned)v[i]);
        }
        __syncthreads();

        // ---- h @ W_h partials: 8 rows x 25 k x 4 cols, weights in registers ----
        {
            #pragma unroll
            for (int r = 0; r < RPW; ++r) {
                float ax = 0.f, ay = 0.f, az = 0.f, aw = 0.f;
                #pragma unroll
                for (int j = 0; j < KLEN; ++j) {
                    float hv = h_l[r][kc * KLEN + j];
                    ax += hv * w[j].x; ay += hv * w[j].y;
                    az += hv * w[j].z; aw += hv * w[j].w;
                }
                if (gemm_act) {
                    float4 o; o.x = ax; o.y = ay; o.z = az; o.w = aw;
                    *(float4*)&zp[kc][r][lc0] = o;
                }
            }
        }
        __syncthreads();

        // ---- reduce + gates + tagged h store (160 threads) ----
        if (tid < RPW * UPW) {
            const int b = r0 + g_r;
            float z4[4];
            #pragma unroll
            for (int gg = 0; gg < 4; ++gg) {
                float s = z_pre[gg];
                #pragma unroll
                for (int k2 = 0; k2 < KCH; ++k2) s += zp[k2][g_r][gg * UPW + g_u];
                z4[gg] = s;
            }
            float ig = sigm(z4[0]);
            float jg = tanh_(z4[1]);
            float fg = sigm(z4[2] + 1.0f);   // FORGET_BIAS
            float og = sigm(z4[3]);
            float c_old = c_l[g_r][g_u];
            float c_new = c_old * fg + ig * jg;
            float h_new = tanh_(c_new) * og;
            bool upd = (t < mylen);
            float h_old = h_l[g_r][u0 + g_u];
            float ho = upd ? h_new : h_old;
            // publish h_t immediately (tag t+1, parity (t+1)&1) — fire & forget
            ull pk = ((ull)(unsigned)(t + 1) << 32) | (ull)__float_as_uint(ho);
            __hip_atomic_store(
                ex + (((size_t)((t + 1) & 1) * GR + rg) * RPW + g_r) * HU + u0 + g_u,
                pk, __ATOMIC_RELAXED, __HIP_MEMORY_SCOPE_AGENT);
            float co = upd ? c_new : c_old;
            c_l[g_r][g_u] = co;
            if (tc == CHUNK - 1) hfin[(size_t)b * HU + u0 + g_u] = ho;
        }
        // no barrier here: next-iter h_l/zp hazards are fenced by the poll
        // protocol (own slots fresh only after own store) and the post-stage
        // __syncthreads.
    }
    if (tid < RPW * UPW)
        cst[(size_t)(r0 + g_r) * HU + u0 + g_u] = c_l[g_r][g_u];
}

// ---------------------------------------------------------------------------
// Phase 3: logits = h_final @ W_dense + b_dense; log-softmax NLL; mean loss.
// One wave per batch row. h_final is the plain-copy hfin buffer.
// ---------------------------------------------------------------------------
__global__ __launch_bounds__(64) void cls_kernel(
    const float* __restrict__ hfin, const float* __restrict__ Wd,
    const float* __restrict__ bd, const int* __restrict__ labels,
    float* __restrict__ out)
{
    const int b = blockIdx.x;
    const int ln = threadIdx.x;
    const float* h = hfin + (size_t)b * HU;
    float p0 = 0.f, p1 = 0.f, p2 = 0.f;
    for (int k = ln; k < HU; k += 64) {
        float hv = h[k];
        p0 += hv * Wd[k * 3 + 0];
        p1 += hv * Wd[k * 3 + 1];
        p2 += hv * Wd[k * 3 + 2];
    }
    #pragma unroll
    for (int off = 32; off > 0; off >>= 1) {
        p0 += __shfl_down(p0, off);
        p1 += __shfl_down(p1, off);
        p2 += __shfl_down(p2, off);
    }
    if (ln == 0) {
        float l0 = p0 + bd[0], l1 = p1 + bd[1], l2 = p2 + bd[2];
        float m = fmaxf(l0, fmaxf(l1, l2));
        float lse = m + logf(__expf(l0 - m) + __expf(l1 - m) + __expf(l2 - m));
        int lab = labels[b];
        float sel = (lab == 0) ? l0 : ((lab == 1) ? l1 : l2);
        float nll = lse - sel;
        out[1 + b * 3 + 0] = l0;
        out[1 + b * 3 + 1] = l1;
        out[1 + b * 3 + 2] = l2;
        atomicAdd(out, nll * (1.0f / BB));
    }
}

// ---------------------------------------------------------------------------
extern "C" void kernel_launch(void* const* d_in, const int* in_sizes, int n_in,
                              void* d_out, int out_size, void* d_ws, size_t ws_size,
                              hipStream_t stream) {
    const int*   ids  = (const int*)d_in[0];
    const int*   lens = (const int*)d_in[1];
    const int*   labs = (const int*)d_in[2];
    const float* emb  = (const float*)d_in[3];
    const float* Wl   = (const float*)d_in[4];
    const float* bl   = (const float*)d_in[5];
    const float* Wd   = (const float*)d_in[6];
    const float* bd   = (const float*)d_in[7];
    float* out = (float*)d_out;

    float* zx   = (float*)d_ws;
    ull*   ex   = (ull*)(zx + ZX_F);
    float* cst  = (float*)(ex + EX_W);
    float* hfin = cst + CST_F;

    {   // zero exchange tags / c state / out[0]
        int n = (int)((EX_W + 255) / 256);
        init_kernel<<<n, 256, 0, stream>>>(ex, cst, out);
    }
    for (int c = 0; c < NCHUNK; ++c) {
        int t0 = c * CHUNK;
        zx_gemm<<<dim3(32, 15), 256, 0, stream>>>(emb, ids, Wl, bl, zx, t0);
        lstm_rec<<<GR * GC, 256, 0, stream>>>(zx, Wl, lens, ex, cst, hfin, t0);
    }
    cls_kernel<<<BB, 64, 0, stream>>>(hfin, Wd, bd, labs, out);
}

// Round 4
// 3378.336 us; speedup vs baseline: 1.1453x; 1.1453x over previous
//
#include <hip/hip_runtime.h>
#include <hip/hip_bf16.h>
#include <math.h>

// Problem constants
#define VV   32000
#define DD   300
#define HU   300
#define NC   3
#define BB   128
#define TT   512
#define N4H  1200
#define CHUNK 64
#define NCHUNK (TT / CHUNK)

// Recurrent kernel partition
#define GC   15   // col groups (units)
#define GR   16   // row groups
#define RPW  8    // rows per WG (BB/GR)
#define UPW  20   // units per WG (HU/GC)
#define KCH  12   // k-chunks (threads 0..239 active in GEMM)
#define KLEN 25   // k per chunk (KCH*KLEN = 300)

// Workspace layout: [zx (float)][ex (ulong, tagged h exchange)][cst][hfin]
static constexpr size_t ZX_F   = (size_t)BB * CHUNK * N4H;   // 9,830,400 floats
static constexpr size_t EX_W   = (size_t)2 * GR * RPW * HU;  // 76,800 ulongs
static constexpr size_t CST_F  = (size_t)BB * HU;            // 38,400 floats
static constexpr size_t HFIN_F = (size_t)BB * HU;            // 38,400 floats

typedef __attribute__((ext_vector_type(8))) short bf16x8;
typedef __attribute__((ext_vector_type(4))) float f32x4;
typedef unsigned long long ull;

__device__ __forceinline__ short f2bf(float f) {
    unsigned u = __float_as_uint(f);
    u += 0x7fff + ((u >> 16) & 1);   // round-to-nearest-even
    return (short)(u >> 16);
}
__device__ __forceinline__ float sigm(float x) { return 1.f / (1.f + __expf(-x)); }
__device__ __forceinline__ float tanh_(float x) { return 1.f - 2.f / (__expf(2.f * x) + 1.f); }

// ---------------------------------------------------------------------------
// init: zero exchange tags, c state, out[0]  (ws is poisoned 0xAA every launch)
// ---------------------------------------------------------------------------
__global__ void init_kernel(ull* __restrict__ ex, float* __restrict__ cst,
                            float* __restrict__ out) {
    size_t i = (size_t)blockIdx.x * 256 + threadIdx.x;
    if (i < EX_W) ex[i] = 0ull;
    if (i < CST_F) cst[i] = 0.f;
    if (i == 0) out[0] = 0.f;
}

// ---------------------------------------------------------------------------
// Phase 1: zx[b][tc][n] = emb[ids[b][t0+tc]] @ W_lstm[0:300] + b_lstm   (bf16 MFMA)
// WG tile: M=256 rows, N=80 cols, K=320 (300 zero-padded). 4 waves, wave = 64x80.
// grid = (8192/256, 1200/80) = (32, 15)
// ---------------------------------------------------------------------------
__global__ __launch_bounds__(256) void zx_gemm(
    const float* __restrict__ emb, const int* __restrict__ ids,
    const float* __restrict__ Wl, const float* __restrict__ bl,
    float* __restrict__ zx, int t0)
{
    __shared__ short A_l[256 * 40];   // [row][k] pad 32->40 shorts
    __shared__ short B_l[80 * 40];    // [col][k] (transposed)
    __shared__ int   ids_l[256];

    const int tid = threadIdx.x;
    const int m0  = blockIdx.x * 256;
    const int n0  = blockIdx.y * 80;
    const int wv  = tid >> 6, ln = tid & 63;

    {   // per-row embedding id
        int m = m0 + tid;
        int b = m >> 6, tc = m & (CHUNK - 1);
        ids_l[tid] = ids[b * TT + t0 + tc];
    }

    f32x4 acc[4][5];
    for (int i = 0; i < 4; ++i)
        for (int j = 0; j < 5; ++j)
            acc[i][j] = (f32x4){0.f, 0.f, 0.f, 0.f};

    for (int k0 = 0; k0 < 320; k0 += 32) {
        __syncthreads();
        // stage A: 256 rows x 32 k, one row per thread (float4 x8, guard k<300)
        {
            const float* src = emb + (size_t)ids_l[tid] * DD;
            #pragma unroll
            for (int q = 0; q < 8; ++q) {
                int kg = k0 + q * 4;
                float4 v;
                if (kg < DD) v = *(const float4*)(src + kg);
                else         v = make_float4(0.f, 0.f, 0.f, 0.f);
                short4 s; s.x = f2bf(v.x); s.y = f2bf(v.y); s.z = f2bf(v.z); s.w = f2bf(v.w);
                *(short4*)&A_l[tid * 40 + q * 4] = s;
            }
        }
        // stage B (transposed): 80 cols x 32 k. thread: kk=tid>>3, 10 cols each
        {
            int kk = tid >> 3;
            int c0 = (tid & 7) * 10;
            int kg = k0 + kk;
            #pragma unroll
            for (int c = 0; c < 10; ++c) {
                float v = (kg < DD) ? Wl[(size_t)kg * N4H + n0 + c0 + c] : 0.f;
                B_l[(c0 + c) * 40 + kk] = f2bf(v);
            }
        }
        __syncthreads();
        // fragments + MFMA. A[m=lane&15][k=quad*8+j], B[k=quad*8+j][n=lane&15]
        const int koff = (ln >> 4) * 8;
        bf16x8 afr[4], bfr[5];
        #pragma unroll
        for (int mt = 0; mt < 4; ++mt) {
            int row = wv * 64 + mt * 16 + (ln & 15);
            afr[mt] = *(const bf16x8*)&A_l[row * 40 + koff];
        }
        #pragma unroll
        for (int nt = 0; nt < 5; ++nt) {
            int col = nt * 16 + (ln & 15);
            bfr[nt] = *(const bf16x8*)&B_l[col * 40 + koff];
        }
        #pragma unroll
        for (int mt = 0; mt < 4; ++mt)
            #pragma unroll
            for (int nt = 0; nt < 5; ++nt)
                acc[mt][nt] = __builtin_amdgcn_mfma_f32_16x16x32_bf16(
                    afr[mt], bfr[nt], acc[mt][nt], 0, 0, 0);
    }
    // epilogue: C row=(lane>>4)*4+reg, col=lane&15; add bias
    #pragma unroll
    for (int mt = 0; mt < 4; ++mt) {
        #pragma unroll
        for (int nt = 0; nt < 5; ++nt) {
            #pragma unroll
            for (int rg = 0; rg < 4; ++rg) {
                int row = m0 + wv * 64 + mt * 16 + (ln >> 4) * 4 + rg;
                int col = n0 + nt * 16 + (ln & 15);
                zx[(size_t)row * N4H + col] = acc[mt][nt][rg] + bl[col];
            }
        }
    }
}

// ---------------------------------------------------------------------------
// Phase 2: persistent recurrent kernel. 240 WGs = 16 row-groups x 15 col-groups.
// W_h slice in registers (thread owns 4 cols x 25 k = 100 VGPRs).
//
// Sync: ONE one-way IC trip. h word = (tag<<32 | f32 bits), stored with one
// relaxed agent-scope 8-B atomic (atomic per word -> no drain, no flag).
// Poll is COALESCED: word i = tid + 256*k (consecutive lanes -> consecutive
// words). Pass 1 writes FRESH words straight to LDS and records a stale mask
// (stale words hold h_{s-3} — must NOT be written, the previous step's gate
// lanes may still read h_old from that LDS slot). Pass 2 spins per stale word.
// Per-word ordering (slot rewritten at s+2 only after the whole row-group
// published s+1, which is after everyone consumed s) makes this fence-free
// safe with no ABA.
// ---------------------------------------------------------------------------
__global__ __launch_bounds__(256, 1) void lstm_rec(
    const float* __restrict__ zx, const float* __restrict__ Wl,
    const int* __restrict__ lens, ull* __restrict__ ex,
    float* __restrict__ cst, float* __restrict__ hfin, int t0)
{
    const int tid = threadIdx.x;
    const int rg  = blockIdx.x % GR;
    const int cgi = blockIdx.x / GR;
    const int r0  = rg * RPW;
    const int u0  = cgi * UPW;

    // GEMM role: cc in 0..19 (4 cols), kc in 0..11 (25 k); tid>=240 idle in GEMM
    const int cc = tid % 20;
    int kc = tid / 20;
    const bool gemm_act = (kc < KCH);
    if (!gemm_act) kc = KCH - 1;      // clamp so weight loads stay in-bounds

    // local col -> global gate col (4 consecutive cols never span a gate: 20%4==0)
    const int lc0  = cc * 4;
    const int gate = lc0 / UPW;
    const int ncol = 300 * gate + u0 + (lc0 % UPW);

    // W_h slice: unconditional load -> full register residency
    float4 w[KLEN];
    #pragma unroll
    for (int j = 0; j < KLEN; ++j) {
        int kh = kc * KLEN + j;  // h index
        w[j] = *(const float4*)(Wl + (size_t)(DD + kh) * N4H + ncol);
    }

    __shared__ float h_l[RPW][304];          // staged h_{t-1}
    __shared__ float zp[KCH][RPW][84];       // k-chunk partials (pad 80->84)
    __shared__ float c_l[RPW][UPW];          // private cell state slice

    // gate role (tid < 160): u = tid%20, r = tid/20
    const int g_u = tid % UPW, g_r = tid / UPW;
    int mylen = 0;
    if (tid < RPW * UPW) {
        c_l[g_r][g_u] = cst[(size_t)(r0 + g_r) * HU + u0 + g_u];
        mylen = lens[r0 + g_r];
    }
    __syncthreads();

    for (int tc = 0; tc < CHUNK; ++tc) {
        const int t = t0 + tc;

        // prefetch zx for this step (independent of h; normal cached loads)
        float z_pre[4];
        if (tid < RPW * UPW) {
            const float* zrow = zx + ((size_t)(r0 + g_r) * CHUNK + tc) * N4H;
            #pragma unroll
            for (int gg = 0; gg < 4; ++gg)
                z_pre[gg] = zrow[300 * gg + u0 + g_u];
        }

        // ---- stage h_{t-1}: coalesced tagged poll into LDS ----
        if (t == 0) {
            for (int i = tid; i < RPW * HU; i += 256)
                h_l[i / HU][i % HU] = 0.f;
        } else {
            const ull* exb = ex + ((size_t)(t & 1) * GR + rg) * (RPW * HU);
            unsigned stale = 0;
            {   // pass 1: coalesced sweep, fresh words -> LDS, stale -> mask
                int u = tid, r = 0, k = 0;
                for (int i = tid; i < RPW * HU; i += 256, ++k) {
                    ull v = __hip_atomic_load(exb + i, __ATOMIC_RELAXED,
                                              __HIP_MEMORY_SCOPE_AGENT);
                    if ((int)(v >> 32) >= t)
                        h_l[r][u] = __uint_as_float((unsigned)v);
                    else
                        stale |= 1u << k;
                    u += 256; if (u >= HU) { u -= HU; ++r; }
                }
            }
            // pass 2: spin on rare stragglers individually
            while (stale) {
                int k = __builtin_ctz(stale);
                stale &= stale - 1;
                int i = tid + (k << 8);
                ull v;
                for (;;) {
                    v = __hip_atomic_load(exb + i, __ATOMIC_RELAXED,
                                          __HIP_MEMORY_SCOPE_AGENT);
                    if ((int)(v >> 32) >= t) break;
                    __builtin_amdgcn_s_sleep(1);
                }
                h_l[i / HU][i % HU] = __uint_as_float((unsigned)v);
            }
        }
        __syncthreads();

        // ---- h @ W_h partials: 8 rows x 25 k x 4 cols, weights in registers ----
        {
            #pragma unroll
            for (int r = 0; r < RPW; ++r) {
                float ax = 0.f, ay = 0.f, az = 0.f, aw = 0.f;
                #pragma unroll
                for (int j = 0; j < KLEN; ++j) {
                    float hv = h_l[r][kc * KLEN + j];
                    ax += hv * w[j].x; ay += hv * w[j].y;
                    az += hv * w[j].z; aw += hv * w[j].w;
                }
                if (gemm_act) {
                    float4 o; o.x = ax; o.y = ay; o.z = az; o.w = aw;
                    *(float4*)&zp[kc][r][lc0] = o;
                }
            }
        }
        __syncthreads();

        // ---- reduce + gates + tagged h store (160 threads) ----
        if (tid < RPW * UPW) {
            const int b = r0 + g_r;
            float z4[4];
            #pragma unroll
            for (int gg = 0; gg < 4; ++gg) {
                float s = z_pre[gg];
                #pragma unroll
                for (int k2 = 0; k2 < KCH; ++k2) s += zp[k2][g_r][gg * UPW + g_u];
                z4[gg] = s;
            }
            float ig = sigm(z4[0]);
            float jg = tanh_(z4[1]);
            float fg = sigm(z4[2] + 1.0f);   // FORGET_BIAS
            float og = sigm(z4[3]);
            float c_old = c_l[g_r][g_u];
            float c_new = c_old * fg + ig * jg;
            float h_new = tanh_(c_new) * og;
            bool upd = (t < mylen);
            float h_old = h_l[g_r][u0 + g_u];
            float ho = upd ? h_new : h_old;
            // publish h_t immediately (tag t+1, parity (t+1)&1) — fire & forget
            ull pk = ((ull)(unsigned)(t + 1) << 32) | (ull)__float_as_uint(ho);
            __hip_atomic_store(
                ex + (((size_t)((t + 1) & 1) * GR + rg) * RPW + g_r) * HU + u0 + g_u,
                pk, __ATOMIC_RELAXED, __HIP_MEMORY_SCOPE_AGENT);
            float co = upd ? c_new : c_old;
            c_l[g_r][g_u] = co;
            if (tc == CHUNK - 1) hfin[(size_t)b * HU + u0 + g_u] = ho;
        }
        // no trailing barrier: per-word poll ordering covers h_l hazards;
        // zp hazards covered by the post-poll barrier.
    }
    if (tid < RPW * UPW)
        cst[(size_t)(r0 + g_r) * HU + u0 + g_u] = c_l[g_r][g_u];
}

// ---------------------------------------------------------------------------
// Phase 3: logits = h_final @ W_dense + b_dense; log-softmax NLL; mean loss.
// One wave per batch row.
// ---------------------------------------------------------------------------
__global__ __launch_bounds__(64) void cls_kernel(
    const float* __restrict__ hfin, const float* __restrict__ Wd,
    const float* __restrict__ bd, const int* __restrict__ labels,
    float* __restrict__ out)
{
    const int b = blockIdx.x;
    const int ln = threadIdx.x;
    const float* h = hfin + (size_t)b * HU;
    float p0 = 0.f, p1 = 0.f, p2 = 0.f;
    for (int k = ln; k < HU; k += 64) {
        float hv = h[k];
        p0 += hv * Wd[k * 3 + 0];
        p1 += hv * Wd[k * 3 + 1];
        p2 += hv * Wd[k * 3 + 2];
    }
    #pragma unroll
    for (int off = 32; off > 0; off >>= 1) {
        p0 += __shfl_down(p0, off);
        p1 += __shfl_down(p1, off);
        p2 += __shfl_down(p2, off);
    }
    if (ln == 0) {
        float l0 = p0 + bd[0], l1 = p1 + bd[1], l2 = p2 + bd[2];
        float m = fmaxf(l0, fmaxf(l1, l2));
        float lse = m + logf(__expf(l0 - m) + __expf(l1 - m) + __expf(l2 - m));
        int lab = labels[b];
        float sel = (lab == 0) ? l0 : ((lab == 1) ? l1 : l2);
        float nll = lse - sel;
        out[1 + b * 3 + 0] = l0;
        out[1 + b * 3 + 1] = l1;
        out[1 + b * 3 + 2] = l2;
        atomicAdd(out, nll * (1.0f / BB));
    }
}

// ---------------------------------------------------------------------------
extern "C" void kernel_launch(void* const* d_in, const int* in_sizes, int n_in,
                              void* d_out, int out_size, void* d_ws, size_t ws_size,
                              hipStream_t stream) {
    const int*   ids  = (const int*)d_in[0];
    const int*   lens = (const int*)d_in[1];
    const int*   labs = (const int*)d_in[2];
    const float* emb  = (const float*)d_in[3];
    const float* Wl   = (const float*)d_in[4];
    const float* bl   = (const float*)d_in[5];
    const float* Wd   = (const float*)d_in[6];
    const float* bd   = (const float*)d_in[7];
    float* out = (float*)d_out;

    float* zx   = (float*)d_ws;
    ull*   ex   = (ull*)(zx + ZX_F);
    float* cst  = (float*)(ex + EX_W);
    float* hfin = cst + CST_F;

    {   // zero exchange tags / c state / out[0]
        int n = (int)((EX_W + 255) / 256);
        init_kernel<<<n, 256, 0, stream>>>(ex, cst, out);
    }
    for (int c = 0; c < NCHUNK; ++c) {
        int t0 = c * CHUNK;
        zx_gemm<<<dim3(32, 15), 256, 0, stream>>>(emb, ids, Wl, bl, zx, t0);
        lstm_rec<<<GR * GC, 256, 0, stream>>>(zx, Wl, lens, ex, cst, hfin, t0);
    }
    cls_kernel<<<BB, 64, 0, stream>>>(hfin, Wd, bd, labs, out);
}

// Round 5
// 2758.135 us; speedup vs baseline: 1.4028x; 1.2249x over previous
//
#include <hip/hip_runtime.h>
#include <hip/hip_bf16.h>
#include <math.h>

// Problem constants
#define VV   32000
#define DD   300
#define HU   300
#define NC   3
#define BB   128
#define TT   512
#define N4H  1200
#define CHUNK 64
#define NCHUNK (TT / CHUNK)

// Recurrent kernel partition
#define GC   15   // col groups (units)
#define GR   16   // row groups
#define RPW  8    // rows per WG (BB/GR)
#define UPW  20   // units per WG (HU/GC)
#define KCH  12   // k-chunks (threads 0..239 active in GEMM)
#define KLEN 25   // k per chunk (KCH*KLEN = 300)

// Workspace layout: [zx (float)][ex (ulong, tagged h exchange)][cst][hfin]
static constexpr size_t ZX_F   = (size_t)BB * CHUNK * N4H;   // 9,830,400 floats
static constexpr size_t EX_W   = (size_t)2 * GR * RPW * HU;  // 76,800 ulongs
static constexpr size_t CST_F  = (size_t)BB * HU;            // 38,400 floats
static constexpr size_t HFIN_F = (size_t)BB * HU;            // 38,400 floats

typedef __attribute__((ext_vector_type(8))) short bf16x8;
typedef __attribute__((ext_vector_type(4))) float f32x4;
typedef unsigned long long ull;

__device__ __forceinline__ short f2bf(float f) {
    unsigned u = __float_as_uint(f);
    u += 0x7fff + ((u >> 16) & 1);   // round-to-nearest-even
    return (short)(u >> 16);
}
__device__ __forceinline__ float sigm(float x) { return 1.f / (1.f + __expf(-x)); }
__device__ __forceinline__ float tanh_(float x) { return 1.f - 2.f / (__expf(2.f * x) + 1.f); }

// ---------------------------------------------------------------------------
// init: zero exchange tags, c state, out[0]  (ws is poisoned 0xAA every launch)
// ---------------------------------------------------------------------------
__global__ void init_kernel(ull* __restrict__ ex, float* __restrict__ cst,
                            float* __restrict__ out) {
    size_t i = (size_t)blockIdx.x * 256 + threadIdx.x;
    if (i < EX_W) ex[i] = 0ull;
    if (i < CST_F) cst[i] = 0.f;
    if (i == 0) out[0] = 0.f;
}

// ---------------------------------------------------------------------------
// Phase 1: zx[b][tc][n] = emb[ids[b][t0+tc]] @ W_lstm[0:300] + b_lstm   (bf16 MFMA)
// WG tile: M=256 rows, N=80 cols, K=320 (300 zero-padded). 4 waves, wave = 64x80.
// grid = (8192/256, 1200/80) = (32, 15)
// ---------------------------------------------------------------------------
__global__ __launch_bounds__(256) void zx_gemm(
    const float* __restrict__ emb, const int* __restrict__ ids,
    const float* __restrict__ Wl, const float* __restrict__ bl,
    float* __restrict__ zx, int t0)
{
    __shared__ short A_l[256 * 40];   // [row][k] pad 32->40 shorts
    __shared__ short B_l[80 * 40];    // [col][k] (transposed)
    __shared__ int   ids_l[256];

    const int tid = threadIdx.x;
    const int m0  = blockIdx.x * 256;
    const int n0  = blockIdx.y * 80;
    const int wv  = tid >> 6, ln = tid & 63;

    {   // per-row embedding id
        int m = m0 + tid;
        int b = m >> 6, tc = m & (CHUNK - 1);
        ids_l[tid] = ids[b * TT + t0 + tc];
    }

    f32x4 acc[4][5];
    for (int i = 0; i < 4; ++i)
        for (int j = 0; j < 5; ++j)
            acc[i][j] = (f32x4){0.f, 0.f, 0.f, 0.f};

    for (int k0 = 0; k0 < 320; k0 += 32) {
        __syncthreads();
        // stage A: 256 rows x 32 k, one row per thread (float4 x8, guard k<300)
        {
            const float* src = emb + (size_t)ids_l[tid] * DD;
            #pragma unroll
            for (int q = 0; q < 8; ++q) {
                int kg = k0 + q * 4;
                float4 v;
                if (kg < DD) v = *(const float4*)(src + kg);
                else         v = make_float4(0.f, 0.f, 0.f, 0.f);
                short4 s; s.x = f2bf(v.x); s.y = f2bf(v.y); s.z = f2bf(v.z); s.w = f2bf(v.w);
                *(short4*)&A_l[tid * 40 + q * 4] = s;
            }
        }
        // stage B (transposed): 80 cols x 32 k. thread: kk=tid>>3, 10 cols each
        {
            int kk = tid >> 3;
            int c0 = (tid & 7) * 10;
            int kg = k0 + kk;
            #pragma unroll
            for (int c = 0; c < 10; ++c) {
                float v = (kg < DD) ? Wl[(size_t)kg * N4H + n0 + c0 + c] : 0.f;
                B_l[(c0 + c) * 40 + kk] = f2bf(v);
            }
        }
        __syncthreads();
        // fragments + MFMA. A[m=lane&15][k=quad*8+j], B[k=quad*8+j][n=lane&15]
        const int koff = (ln >> 4) * 8;
        bf16x8 afr[4], bfr[5];
        #pragma unroll
        for (int mt = 0; mt < 4; ++mt) {
            int row = wv * 64 + mt * 16 + (ln & 15);
            afr[mt] = *(const bf16x8*)&A_l[row * 40 + koff];
        }
        #pragma unroll
        for (int nt = 0; nt < 5; ++nt) {
            int col = nt * 16 + (ln & 15);
            bfr[nt] = *(const bf16x8*)&B_l[col * 40 + koff];
        }
        #pragma unroll
        for (int mt = 0; mt < 4; ++mt)
            #pragma unroll
            for (int nt = 0; nt < 5; ++nt)
                acc[mt][nt] = __builtin_amdgcn_mfma_f32_16x16x32_bf16(
                    afr[mt], bfr[nt], acc[mt][nt], 0, 0, 0);
    }
    // epilogue: C row=(lane>>4)*4+reg, col=lane&15; add bias
    #pragma unroll
    for (int mt = 0; mt < 4; ++mt) {
        #pragma unroll
        for (int nt = 0; nt < 5; ++nt) {
            #pragma unroll
            for (int rg = 0; rg < 4; ++rg) {
                int row = m0 + wv * 64 + mt * 16 + (ln >> 4) * 4 + rg;
                int col = n0 + nt * 16 + (ln & 15);
                zx[(size_t)row * N4H + col] = acc[mt][nt][rg] + bl[col];
            }
        }
    }
}

// ---------------------------------------------------------------------------
// Phase 2: persistent recurrent kernel. 240 WGs = 16 row-groups x 15 col-groups.
// W_h slice in registers (thread owns 4 cols x 25 k = 100 VGPRs, PINNED via
// asm so the compiler cannot rematerialize the loads each step).
//
// Sync: ONE one-way IC trip. h word = (tag<<32 | f32 bits), stored with one
// relaxed agent-scope 8-B atomic (atomic per word -> no drain, no flag).
// Poll is coalesced (word i = tid + 256*k) AND batched: every sweep issues
// loads for ALL pending words back-to-back (one latency), then accepts fresh
// words into LDS. No per-word serial spinning (round-4 bug: steady state has
// all words stale on the first sweep, so serial re-poll = ~10 IC latencies).
// Per-word monotone-tag ordering makes slot overwrite race-free, no fences.
// ---------------------------------------------------------------------------
__global__ __launch_bounds__(256, 1) void lstm_rec(
    const float* __restrict__ zx, const float* __restrict__ Wl,
    const int* __restrict__ lens, ull* __restrict__ ex,
    float* __restrict__ cst, float* __restrict__ hfin, int t0)
{
    const int tid = threadIdx.x;
    const int rg  = blockIdx.x % GR;
    const int cgi = blockIdx.x / GR;
    const int r0  = rg * RPW;
    const int u0  = cgi * UPW;

    // GEMM role: cc in 0..19 (4 cols), kc in 0..11 (25 k); tid>=240 idle in GEMM
    const int cc = tid % 20;
    int kc = tid / 20;
    const bool gemm_act = (kc < KCH);
    if (!gemm_act) kc = KCH - 1;      // clamp so weight loads stay in-bounds

    // local col -> global gate col (4 consecutive cols never span a gate: 20%4==0)
    const int lc0  = cc * 4;
    const int gate = lc0 / UPW;
    const int ncol = 300 * gate + u0 + (lc0 % UPW);

    // W_h slice: load once, then PIN in VGPRs (asm output can't be remat'd)
    float4 w[KLEN];
    #pragma unroll
    for (int j = 0; j < KLEN; ++j) {
        int kh = kc * KLEN + j;  // h index
        w[j] = *(const float4*)(Wl + (size_t)(DD + kh) * N4H + ncol);
    }
    #pragma unroll
    for (int j = 0; j < KLEN; ++j)
        asm volatile("" : "+v"(w[j].x), "+v"(w[j].y), "+v"(w[j].z), "+v"(w[j].w));

    __shared__ float h_l[RPW][304];          // staged h_{t-1}
    __shared__ float zp[KCH][RPW][84];       // k-chunk partials (pad 80->84)
    __shared__ float c_l[RPW][UPW];          // private cell state slice

    // gate role (tid < 160): u = tid%20, r = tid/20
    const int g_u = tid % UPW, g_r = tid / UPW;
    int mylen = 0;
    if (tid < RPW * UPW) {
        c_l[g_r][g_u] = cst[(size_t)(r0 + g_r) * HU + u0 + g_u];
        mylen = lens[r0 + g_r];
    }
    __syncthreads();

    for (int tc = 0; tc < CHUNK; ++tc) {
        const int t = t0 + tc;

        // prefetch zx for this step (independent of h; normal cached loads)
        float z_pre[4];
        if (tid < RPW * UPW) {
            const float* zrow = zx + ((size_t)(r0 + g_r) * CHUNK + tc) * N4H;
            #pragma unroll
            for (int gg = 0; gg < 4; ++gg)
                z_pre[gg] = zrow[300 * gg + u0 + g_u];
        }

        // ---- stage h_{t-1}: coalesced BATCHED tagged poll into LDS ----
        if (t == 0) {
            for (int i = tid; i < RPW * HU; i += 256)
                h_l[i / HU][i % HU] = 0.f;
        } else {
            const ull* exb = ex + ((size_t)(t & 1) * GR + rg) * (RPW * HU);
            unsigned pend = (tid < (RPW * HU - 9 * 256)) ? 0x3FFu : 0x1FFu;
            do {
                ull v[10];
                #pragma unroll
                for (int k = 0; k < 10; ++k)
                    if ((pend >> k) & 1)
                        v[k] = __hip_atomic_load(exb + tid + (k << 8),
                                                 __ATOMIC_RELAXED,
                                                 __HIP_MEMORY_SCOPE_AGENT);
                unsigned got = 0;
                #pragma unroll
                for (int k = 0; k < 10; ++k) {
                    if (((pend >> k) & 1) && (int)(v[k] >> 32) >= t) {
                        int i = tid + (k << 8);
                        h_l[i / HU][i % HU] = __uint_as_float((unsigned)v[k]);
                        got |= 1u << k;
                    }
                }
                pend &= ~got;
                if (pend) __builtin_amdgcn_s_sleep(1);
            } while (pend);
        }
        __syncthreads();

        // ---- h @ W_h partials: 8 rows x 25 k x 4 cols, weights in registers ----
        {
            #pragma unroll
            for (int r = 0; r < RPW; ++r) {
                float ax = 0.f, ay = 0.f, az = 0.f, aw = 0.f;
                #pragma unroll
                for (int j = 0; j < KLEN; ++j) {
                    float hv = h_l[r][kc * KLEN + j];
                    ax += hv * w[j].x; ay += hv * w[j].y;
                    az += hv * w[j].z; aw += hv * w[j].w;
                }
                if (gemm_act) {
                    float4 o; o.x = ax; o.y = ay; o.z = az; o.w = aw;
                    *(float4*)&zp[kc][r][lc0] = o;
                }
            }
        }
        __syncthreads();

        // ---- reduce + gates + tagged h store (160 threads) ----
        if (tid < RPW * UPW) {
            const int b = r0 + g_r;
            float z4[4];
            #pragma unroll
            for (int gg = 0; gg < 4; ++gg) {
                float s = z_pre[gg];
                #pragma unroll
                for (int k2 = 0; k2 < KCH; ++k2) s += zp[k2][g_r][gg * UPW + g_u];
                z4[gg] = s;
            }
            float ig = sigm(z4[0]);
            float jg = tanh_(z4[1]);
            float fg = sigm(z4[2] + 1.0f);   // FORGET_BIAS
            float og = sigm(z4[3]);
            float c_old = c_l[g_r][g_u];
            float c_new = c_old * fg + ig * jg;
            float h_new = tanh_(c_new) * og;
            bool upd = (t < mylen);
            float h_old = h_l[g_r][u0 + g_u];
            float ho = upd ? h_new : h_old;
            // publish h_t immediately (tag t+1, parity (t+1)&1) — fire & forget
            ull pk = ((ull)(unsigned)(t + 1) << 32) | (ull)__float_as_uint(ho);
            __hip_atomic_store(
                ex + (((size_t)((t + 1) & 1) * GR + rg) * RPW + g_r) * HU + u0 + g_u,
                pk, __ATOMIC_RELAXED, __HIP_MEMORY_SCOPE_AGENT);
            float co = upd ? c_new : c_old;
            c_l[g_r][g_u] = co;
            if (tc == CHUNK - 1) hfin[(size_t)b * HU + u0 + g_u] = ho;
        }
        // no trailing barrier: per-word poll ordering covers h_l hazards;
        // zp hazards covered by the post-poll barrier.
    }
    if (tid < RPW * UPW)
        cst[(size_t)(r0 + g_r) * HU + u0 + g_u] = c_l[g_r][g_u];
}

// ---------------------------------------------------------------------------
// Phase 3: logits = h_final @ W_dense + b_dense; log-softmax NLL; mean loss.
// One wave per batch row.
// ---------------------------------------------------------------------------
__global__ __launch_bounds__(64) void cls_kernel(
    const float* __restrict__ hfin, const float* __restrict__ Wd,
    const float* __restrict__ bd, const int* __restrict__ labels,
    float* __restrict__ out)
{
    const int b = blockIdx.x;
    const int ln = threadIdx.x;
    const float* h = hfin + (size_t)b * HU;
    float p0 = 0.f, p1 = 0.f, p2 = 0.f;
    for (int k = ln; k < HU; k += 64) {
        float hv = h[k];
        p0 += hv * Wd[k * 3 + 0];
        p1 += hv * Wd[k * 3 + 1];
        p2 += hv * Wd[k * 3 + 2];
    }
    #pragma unroll
    for (int off = 32; off > 0; off >>= 1) {
        p0 += __shfl_down(p0, off);
        p1 += __shfl_down(p1, off);
        p2 += __shfl_down(p2, off);
    }
    if (ln == 0) {
        float l0 = p0 + bd[0], l1 = p1 + bd[1], l2 = p2 + bd[2];
        float m = fmaxf(l0, fmaxf(l1, l2));
        float lse = m + logf(__expf(l0 - m) + __expf(l1 - m) + __expf(l2 - m));
        int lab = labels[b];
        float sel = (lab == 0) ? l0 : ((lab == 1) ? l1 : l2);
        float nll = lse - sel;
        out[1 + b * 3 + 0] = l0;
        out[1 + b * 3 + 1] = l1;
        out[1 + b * 3 + 2] = l2;
        atomicAdd(out, nll * (1.0f / BB));
    }
}

// ---------------------------------------------------------------------------
extern "C" void kernel_launch(void* const* d_in, const int* in_sizes, int n_in,
                              void* d_out, int out_size, void* d_ws, size_t ws_size,
                              hipStream_t stream) {
    const int*   ids  = (const int*)d_in[0];
    const int*   lens = (const int*)d_in[1];
    const int*   labs = (const int*)d_in[2];
    const float* emb  = (const float*)d_in[3];
    const float* Wl   = (const float*)d_in[4];
    const float* bl   = (const float*)d_in[5];
    const float* Wd   = (const float*)d_in[6];
    const float* bd   = (const float*)d_in[7];
    float* out = (float*)d_out;

    float* zx   = (float*)d_ws;
    ull*   ex   = (ull*)(zx + ZX_F);
    float* cst  = (float*)(ex + EX_W);
    float* hfin = cst + CST_F;

    {   // zero exchange tags / c state / out[0]
        int n = (int)((EX_W + 255) / 256);
        init_kernel<<<n, 256, 0, stream>>>(ex, cst, out);
    }
    for (int c = 0; c < NCHUNK; ++c) {
        int t0 = c * CHUNK;
        zx_gemm<<<dim3(32, 15), 256, 0, stream>>>(emb, ids, Wl, bl, zx, t0);
        lstm_rec<<<GR * GC, 256, 0, stream>>>(zx, Wl, lens, ex, cst, hfin, t0);
    }
    cls_kernel<<<BB, 64, 0, stream>>>(hfin, Wd, bd, labs, out);
}